// Round 5
// baseline (147.644 us; speedup 1.0000x reference)
//
#include <hip/hip_runtime.h>
#include <stdint.h>

#define B_ROWS 4096
#define D_DIM  512
#define N_TOT  8192
#define TEMP_INV 2.0f   // 1/0.5

// kernel-2 geometry: 256x256 tiles, upper-triangular
#define NB2    32       // N_TOT / 256
#define NTRI2  528      // NB2*(NB2+1)/2  (528 % 8 == 0 -> bijective XCD swizzle)
#define KT2    16       // D_DIM / 32 K-tiles

typedef __bf16 bf16x8 __attribute__((ext_vector_type(8)));
typedef float  f32x4  __attribute__((ext_vector_type(4)));
typedef unsigned short ushort8 __attribute__((ext_vector_type(8)));

#define VM_WAIT(N) asm volatile("s_waitcnt vmcnt(" #N ")" ::: "memory")
#define LGKM0()    asm volatile("s_waitcnt lgkmcnt(0)" ::: "memory")
#define BAR()      do { asm volatile("" ::: "memory"); \
                        __builtin_amdgcn_s_barrier();  \
                        asm volatile("" ::: "memory"); } while (0)

__device__ __forceinline__ unsigned short f2bf(float f) {
    union { float f; unsigned int u; } c; c.f = f;
    unsigned int u = c.u;
    return (unsigned short)((u + 0x7fffu + ((u >> 16) & 1u)) >> 16);
}

// async global->LDS, 16B per lane. LDS dest is wave-uniform base + lane*16;
// global source address is per-lane (carries the swizzle).
__device__ __forceinline__ void gl_lds16(const void* g, void* l) {
    __builtin_amdgcn_global_load_lds(
        (__attribute__((address_space(1))) void*)(uintptr_t)g,
        (__attribute__((address_space(3))) void*)(uintptr_t)l,
        16, 0, 0);
}

// ------- kernel 1: fused L2-normalize (write bf16 z) + positive-pair dot -------
__global__ __launch_bounds__(256) void normpos_kernel(
    const float* __restrict__ xi, const float* __restrict__ xj,
    unsigned short* __restrict__ z, float* __restrict__ pos,
    float* __restrict__ rowsum) {
    if (blockIdx.x < N_TOT / 256) rowsum[blockIdx.x * 256 + threadIdx.x] = 0.f;
    const int wid  = threadIdx.x >> 6;
    const int lane = threadIdx.x & 63;
    const int k    = blockIdx.x * 4 + wid;
    const float4* a4 = (const float4*)(xi + (size_t)k * D_DIM);
    const float4* b4 = (const float4*)(xj + (size_t)k * D_DIM);
    float4 va0 = a4[2 * lane], va1 = a4[2 * lane + 1];
    float4 vb0 = b4[2 * lane], vb1 = b4[2 * lane + 1];
    float ssa = va0.x*va0.x + va0.y*va0.y + va0.z*va0.z + va0.w*va0.w
              + va1.x*va1.x + va1.y*va1.y + va1.z*va1.z + va1.w*va1.w;
    float ssb = vb0.x*vb0.x + vb0.y*vb0.y + vb0.z*vb0.z + vb0.w*vb0.w
              + vb1.x*vb1.x + vb1.y*vb1.y + vb1.z*vb1.z + vb1.w*vb1.w;
    float dot = va0.x*vb0.x + va0.y*vb0.y + va0.z*vb0.z + va0.w*vb0.w
              + va1.x*vb1.x + va1.y*vb1.y + va1.z*vb1.z + va1.w*vb1.w;
    #pragma unroll
    for (int m = 32; m >= 1; m >>= 1) {
        ssa += __shfl_xor(ssa, m);
        ssb += __shfl_xor(ssb, m);
        dot += __shfl_xor(dot, m);
    }
    const float rna = 1.0f / fmaxf(sqrtf(ssa), 1e-12f);
    const float rnb = 1.0f / fmaxf(sqrtf(ssb), 1e-12f);
    float av[8] = {va0.x, va0.y, va0.z, va0.w, va1.x, va1.y, va1.z, va1.w};
    float bv[8] = {vb0.x, vb0.y, vb0.z, vb0.w, vb1.x, vb1.y, vb1.z, vb1.w};
    union { ushort8 v; unsigned short s[8]; } oa, ob;
    #pragma unroll
    for (int i = 0; i < 8; ++i) {
        oa.s[i] = f2bf(av[i] * rna);
        ob.s[i] = f2bf(bv[i] * rnb);
    }
    *(ushort8*)(z + (size_t)k * D_DIM + lane * 8) = oa.v;
    *(ushort8*)(z + (size_t)(k + B_ROWS) * D_DIM + lane * 8) = ob.v;
    if (lane == 0) pos[k] = dot * rna * rnb;
}

// -------- kernel 2: v5 — 256x256 tile, 8 waves, phase-split deep pipeline --------
// T3+T4+T5 port of the verified 8-phase template, adapted to K=512:
//   16 K-tiles (BK=32), 2 phases/tile, 16 MFMA per wave per phase.
//   Triple-buffered LDS (3 x 32 KB): stage unit (A- or B-tile, 16 KB, 2 gl_lds/wave)
//   issued ~4 phases before consumption; vmcnt(4) ONCE per tile (never 0 in loop).
// vmcnt publish audit: every wave issues 2 loads to EVERY unit in the same global
//   order [A0,B0,A1,B1,A2,B2,...]; per-wave vmcnt(4) => all its loads through unit
//   B(t+1) have landed; barrier => holds for all waves => tile t+1 fully resident.
// WAR audit: stage of tile t+2 (buf (t+2)%3) is issued in tile t's phases; that
//   buffer's previous tenant (tile t-1) had all ds_reads retired via LGKM0 before
//   tile t-1's closing barrier, which precedes these stage issues.
// Bank conflicts: reuses v0's measured-0-conflict XOR k-chunk swizzle, applied to
//   BOTH stage source and ds_read (rule #21).
__global__ __launch_bounds__(512, 2) void simrow_kernel(
    const unsigned short* __restrict__ z, float* __restrict__ rowsum) {
    __shared__ unsigned short AB[3][2][256 * 32];  // 3 bufs x {A,B} x 16 KB = 96 KB
    __shared__ float rsum[256];
    __shared__ float csum[256];
    const int tid  = threadIdx.x;
    const int lane = tid & 63;
    const int wid  = tid >> 6;

    // XCD-chunked bijective swizzle
    const int t0 = (blockIdx.x & 7) * (NTRI2 / 8) + (blockIdx.x >> 3);

    // linear id -> upper-triangular (bi, bj), bi <= bj
    int bi = (int)(NB2 + 0.5f - sqrtf((NB2 + 0.5f) * (NB2 + 0.5f) - 2.0f * t0));
    if (bi < 0) bi = 0;
    if (bi > NB2 - 1) bi = NB2 - 1;
    while (bi > 0 && (bi * NB2 - bi * (bi - 1) / 2) > t0) --bi;
    while ((bi + 1) * NB2 - (bi + 1) * bi / 2 <= t0) ++bi;
    const int bj = bi + (t0 - (bi * NB2 - bi * (bi - 1) / 2));
    const int row0 = bi * 256;
    const int col0 = bj * 256;
    const bool diag = (bi == bj);

    if (tid < 256) { rsum[tid] = 0.f; csum[tid] = 0.f; }

    const int wr = wid >> 2;   // 0..1 : wave row (128 rows each)
    const int wc = wid & 3;    // 0..3 : wave col (64 cols each)
    f32x4 acc[8][4] = {};

    // ---- staging: unit = one 256x32 tile (16 KB) = 2 gl_lds per wave ----
    // lane -> row_in_16 = lane>>2, chunkpos = lane&3 (16B chunks of a 64B k-slice)
    // source chunk pre-swizzled: c = pos ^ ((row>>1)&3); (row>>1)&3 == (lane>>3)&3
    const int skc = ((lane & 3) ^ ((lane >> 3) & 3)) * 8;
    const unsigned short* gA = z + (size_t)(row0 + wid * 16 + (lane >> 2)) * D_DIM + skc;
    const unsigned short* gB = z + (size_t)(col0 + wid * 16 + (lane >> 2)) * D_DIM + skc;

    auto stageA = [&](int buf, int t) {
        #pragma unroll
        for (int h = 0; h < 2; ++h)
            gl_lds16(gA + (size_t)(h * 128) * D_DIM + t * 32,
                     &AB[buf][0][(h * 128 + wid * 16) * 32]);
    };
    auto stageB = [&](int buf, int t) {  // diag blocks stage B redundantly: uniform vmcnt
        #pragma unroll
        for (int h = 0; h < 2; ++h)
            gl_lds16(gB + (size_t)(h * 128) * D_DIM + t * 32,
                     &AB[buf][1][(h * 128 + wid * 16) * 32]);
    };

    // ---- fragment reads: slot = (kq ^ ((row>>1)&3))*8 ; (row>>1)&3 == (ml>>1)&3 ----
    const int ml   = lane & 15;
    const int kq   = lane >> 4;
    const int slot = (kq ^ ((ml >> 1) & 3)) * 8;

    // prologue: tiles 0,1 in flight; publish tile 0
    stageA(0, 0); stageB(0, 0); stageA(1, 1); stageB(1, 1);
    VM_WAIT(4);
    BAR();

    for (int t = 0; t < KT2; ++t) {
        const int buf = t % 3;
        const unsigned short* A = &AB[buf][0][0];
        const unsigned short* B = &AB[buf][1][0];
        bf16x8 a[4], b[4];

        // -------- phase 0: M-half 0 --------
        #pragma unroll
        for (int j = 0; j < 4; ++j)
            a[j] = *(const bf16x8*)&A[(wr * 128 + j * 16 + ml) * 32 + slot];
        #pragma unroll
        for (int n = 0; n < 4; ++n)
            b[n] = *(const bf16x8*)&B[(wc * 64 + n * 16 + ml) * 32 + slot];
        if (t + 2 < KT2) stageA((t + 2) % 3, t + 2);
        BAR();
        LGKM0();
        __builtin_amdgcn_sched_barrier(0);   // rule #18: pin MFMA below lgkmcnt
        __builtin_amdgcn_s_setprio(1);
        #pragma unroll
        for (int j = 0; j < 4; ++j)
            #pragma unroll
            for (int n = 0; n < 4; ++n)
                acc[j][n] = __builtin_amdgcn_mfma_f32_16x16x32_bf16(
                    a[j], b[n], acc[j][n], 0, 0, 0);
        __builtin_amdgcn_s_setprio(0);
        BAR();

        // -------- phase 1: M-half 1 (b[] reused from registers) --------
        #pragma unroll
        for (int j = 0; j < 4; ++j)
            a[j] = *(const bf16x8*)&A[(wr * 128 + 64 + j * 16 + ml) * 32 + slot];
        if (t + 2 < KT2) stageB((t + 2) % 3, t + 2);
        if (t <= KT2 - 3)      VM_WAIT(4);   // tile t+1 fully landed; t+2 flying
        else if (t == KT2 - 2) VM_WAIT(0);   // drain: tile 15 landed
        BAR();
        LGKM0();
        __builtin_amdgcn_sched_barrier(0);
        __builtin_amdgcn_s_setprio(1);
        #pragma unroll
        for (int j = 0; j < 4; ++j)
            #pragma unroll
            for (int n = 0; n < 4; ++n)
                acc[4 + j][n] = __builtin_amdgcn_mfma_f32_16x16x32_bf16(
                    a[j], b[n], acc[4 + j][n], 0, 0, 0);
        __builtin_amdgcn_s_setprio(0);
        BAR();
    }

    // -------- epilogue: e = exp(2*sim), mask diag; row sums + symmetric col sums --------
    const int quad = lane >> 4;
    const int cl   = lane & 15;
    float colacc[4] = {0.f, 0.f, 0.f, 0.f};
    #pragma unroll
    for (int mi = 0; mi < 8; ++mi) {
        #pragma unroll
        for (int r = 0; r < 4; ++r) {
            const int lrow = wr * 128 + mi * 16 + quad * 4 + r;
            const int irow = row0 + lrow;
            float s = 0.f;
            #pragma unroll
            for (int ni = 0; ni < 4; ++ni) {
                const int jcol = col0 + wc * 64 + ni * 16 + cl;
                float e = __expf(TEMP_INV * acc[mi][ni][r]);
                e = (irow == jcol) ? 0.f : e;
                s += e;
                colacc[ni] += e;
            }
            s += __shfl_xor(s, 1);
            s += __shfl_xor(s, 2);
            s += __shfl_xor(s, 4);
            s += __shfl_xor(s, 8);
            if (cl == 0) atomicAdd(&rsum[lrow], s);
        }
    }
    if (!diag) {
        #pragma unroll
        for (int ni = 0; ni < 4; ++ni) {
            float c = colacc[ni];
            c += __shfl_xor(c, 16);
            c += __shfl_xor(c, 32);
            if (quad == 0) atomicAdd(&csum[wc * 64 + ni * 16 + cl], c);
        }
    }
    __syncthreads();
    if (tid < 256) {
        atomicAdd(&rowsum[row0 + tid], rsum[tid]);
        if (!diag) atomicAdd(&rowsum[col0 + tid], csum[tid]);
    }
}

// ---------------- kernel 3: finalize scalar loss ----------------
__global__ __launch_bounds__(256) void finalize_kernel(
    const float* __restrict__ rowsum, const float* __restrict__ pos,
    float* __restrict__ out) {
    const int t = threadIdx.x;
    float s = 0.f;
    for (int i = t; i < N_TOT; i += 256) s += logf(rowsum[i]);
    float p = 0.f;
    for (int i = t; i < B_ROWS; i += 256) p += pos[i];
    #pragma unroll
    for (int m = 32; m >= 1; m >>= 1) {
        s += __shfl_xor(s, m);
        p += __shfl_xor(p, m);
    }
    __shared__ float ws[4], wp[4];
    if ((t & 63) == 0) { ws[t >> 6] = s; wp[t >> 6] = p; }
    __syncthreads();
    if (t == 0) {
        float tot = ws[0] + ws[1] + ws[2] + ws[3];
        float ptot = wp[0] + wp[1] + wp[2] + wp[3];
        out[0] = tot / (float)N_TOT - ptot * (2.0f * TEMP_INV / (float)N_TOT);
    }
}

extern "C" void kernel_launch(void* const* d_in, const int* in_sizes, int n_in,
                              void* d_out, int out_size, void* d_ws, size_t ws_size,
                              hipStream_t stream) {
    const float* xi = (const float*)d_in[0];
    const float* xj = (const float*)d_in[1];
    float* out = (float*)d_out;
    char* ws = (char*)d_ws;

    unsigned short* z = (unsigned short*)ws;                       // 8 MB bf16
    float* rowsum = (float*)(ws + (size_t)N_TOT * D_DIM * 2);      // 32 KB
    float* pos = rowsum + N_TOT;                                   // 16 KB

    normpos_kernel<<<B_ROWS / 4, 256, 0, stream>>>(xi, xj, z, pos, rowsum);
    simrow_kernel<<<NTRI2, 512, 0, stream>>>(z, rowsum);
    finalize_kernel<<<1, 256, 0, stream>>>(rowsum, pos, out);
}